// Round 15
// baseline (104.800 us; speedup 1.0000x reference)
//
#include <hip/hip_runtime.h>
#include <stdint.h>

#define KCODES  1024
#define CDIM    64
#define SPATIAL 32768
#define NPOS    65536
#define NEL     4194304

// d_out layout (floats), outputs concatenated in reference return order
#define OUT_Q    0
#define OUT_LOSS 4194304
#define OUT_IDX  4194305
#define OUT_SUM  4259841
#define OUT_EMB  4260097

// ws: 64 sets x 4KB {Ah0(ch0-31),Ah1(ch32-63),Al0,Al1} 1KB chunks (lane-linear
// 16x16x32 A-frags, 16 codes/set), then eiE[1024] f32 (-0.5||e||^2) at EIOFF
#define SETB   4096
#define EIOFF  262144
#define BPOS   64
#define NRND   16          // rounds per stream (K-split 4: 16 sets of 16 codes)

typedef _Float16 half8 __attribute__((ext_vector_type(8)));
typedef float    f32x4 __attribute__((ext_vector_type(4)));

// ---- prep: fragment-swizzle codebook into 16-code sets, ei, zero, passthrough ----
__global__ void prep_emb(const float* __restrict__ emb, char* __restrict__ ws,
                         float* __restrict__ out) {
    int gt = blockIdx.x * 256 + threadIdx.x;        // 64 blocks -> 0..16383
    if (gt == 0) out[OUT_LOSS] = 0.f;
    if (gt < 256) out[OUT_SUM + gt] = 0.f;
    {   // embedding passthrough (OUT_EMB odd offset -> scalar stores)
        float4 v = *(const float4*)(emb + (size_t)gt * 4);
        float* o = out + OUT_EMB + (size_t)gt * 4;
        o[0] = v.x; o[1] = v.y; o[2] = v.z; o[3] = v.w;
    }
    if (gt < 8192) {                                 // one (code, 8-ch octet) each
        int k = gt >> 3, oct = gt & 7;
        int set = k >> 4, row = k & 15;
        int s = oct >> 2, g = oct & 3;               // c = s*32 + g*8 + i
        const float* e = emb + (size_t)k * CDIM + oct * 8;
        char* rec = ws + (size_t)set * SETB;
        // A-frag (16x16x32): lane l = g*16+row holds 8 f16 at chunk + l*16
        _Float16* hi = (_Float16*)(rec + s * 1024 + ((g << 4) | row) * 16);
        _Float16* lo = (_Float16*)(rec + 2048 + s * 1024 + ((g << 4) | row) * 16);
        float s2 = 0.f;
        half8 hv, lv;
#pragma unroll
        for (int i = 0; i < 8; ++i) {
            float v = e[i];
            s2 = fmaf(v, v, s2);
            _Float16 h = (_Float16)v;
            hv[i] = h;
            lv[i] = (_Float16)(v - (float)h);
        }
        *(half8*)hi = hv;
        *(half8*)lo = lv;
        s2 += __shfl_xor(s2, 1);                     // reduce over the octet group
        s2 += __shfl_xor(s2, 2);
        s2 += __shfl_xor(s2, 4);
        if (oct == 0) ((float*)(ws + EIOFF))[k] = -0.5f * s2;   // eiE[k]
    }
}

// async global->LDS, 16B per lane
#define GLDS16(GSRC, LDST)                                                     \
    __builtin_amdgcn_global_load_lds(                                          \
        (const __attribute__((address_space(1))) void*)(GSRC),                 \
        (__attribute__((address_space(3))) void*)(LDST), 16, 0, 0)

// ---- main VQ kernel ----
// Grid 1024 x 512 thr (8 waves) = 4 blocks/CU = 8 waves/SIMD (LDS ~38KB,
// VGPR <= 64 via __launch_bounds__(512,8); R13-measured working set 52).
// Block owns 64 positions. Wave (pg,kh): pg=wv&1 owns 32 positions (2 tiles
// of 16), kh=wv>>1 scans a codebook quarter: 16 sets of 16 codes (16x16x32
// f16 MFMA, fp16 2-way split, 3 terms = 12 MFMA/round as two 6-chains).
// Drain-free double-barrier pipeline (R14 + race fix):
//   round r: STAGE(r+1) -> vmcnt(2) (waits only set r; r+1 stays in flight)
//   -> s_barrier#1 (set r complete block-wide) -> consume -> s_barrier#2
//   (all waves' ds_reads of slot r&1 issued => round r+1's STAGE into that
//   slot cannot corrupt them; DMA writeback lands ~100s of cycles later).
// Score = x.e - 0.5||e||^2 via MFMA C-init; argmax == argmin distance.
__global__ __launch_bounds__(512, 8) void vq_kernel(
        const float* __restrict__ in, const float* __restrict__ emb,
        const char* __restrict__ wsA, float* __restrict__ out) {
    __shared__ __align__(16) char ring[4][2][SETB];  // 32KB; xl (16.6KB) aliases
    __shared__ __align__(16) float eiL[KCODES];      // 4KB (-0.5||e||^2, idx==k)
    __shared__ float candS[4][BPOS];                 // per-kh per-pos best
    __shared__ int   candK[4][BPOS];
    __shared__ int   kwin[BPOS];
    __shared__ float lred[8];

    const int tid  = threadIdx.x;
    const int lane = tid & 63, wv = tid >> 6;        // 8 waves
    const int col  = lane & 15, g = lane >> 4;       // C col / row-group
    const int pg   = wv & 1, kh = wv >> 1;           // pos-group / codebook quarter
    const int p0   = blockIdx.x * BPOS;
    const int b    = p0 >> 15;                       // 64-tile never straddles batch
    const int s0   = p0 & 32767;
    const float* xin = in + (size_t)b * (CDIM * SPATIAL) + s0;

    // ---- prologue: x -> xl (aliased on ring), eiL copy ----
    float* xl = (float*)&ring[0][0][0];              // 64 x 65 f32 = 16.6KB
    {
        int p = tid & 63, cq = tid >> 6;             // 8 ch-groups of 8
#pragma unroll
        for (int j = 0; j < 8; ++j) {
            int c = cq * 8 + j;
            xl[c * 65 + p] = xin[(size_t)c * SPATIAL + p];
        }
    }
    eiL[tid]       = ((const float*)(wsA + EIOFF))[tid];
    eiL[tid + 512] = ((const float*)(wsA + EIOFF))[tid + 512];
    __syncthreads();

    // ---- B-frags: 32 positions x 64 ch hi/lo = 32 VGPR (R2-verified layout) ----
    half8 bh[2][2], bl[2][2];                        // [ntile][s]
#pragma unroll
    for (int nt = 0; nt < 2; ++nt)
#pragma unroll
        for (int s = 0; s < 2; ++s) {
            int pp = pg * 32 + nt * 16 + col;
#pragma unroll
            for (int j = 0; j < 8; ++j) {
                int c = s * 32 + g * 8 + j;
                float v = xl[c * 65 + pp];
                _Float16 hh = (_Float16)v;
                bh[nt][s][j] = hh;
                bl[nt][s][j] = (_Float16)(v - (float)hh);
            }
        }
    __syncthreads();                                 // xl dead; ring reusable; vm drained

    // ---- staging: kh-stream = 2 waves (pg 0,1), each stages 2KB of the 4KB set
    const char* myws = wsA + (size_t)kh * NRND * SETB;
#define STAGE(RSET, SLOT) do {                                                 \
        const char* s_ = myws + (size_t)(RSET) * SETB + pg * 2048 + lane * 16; \
        char* d_ = &ring[kh][SLOT][0] + pg * 2048 + lane * 16;                 \
        GLDS16(s_,        d_);                                                 \
        GLDS16(s_ + 1024, d_ + 1024);                                          \
    } while (0)
    STAGE(0, 0);                                     // set 0 in flight

    f32x4 maxS0, maxS1;                              // per-(ntile, r-slot) argmax
    int   maxR0[4], maxR1[4];
#pragma unroll
    for (int r = 0; r < 4; ++r) {
        maxS0[r] = -3.402823466e38f; maxS1[r] = -3.402823466e38f;
        maxR0[r] = 0;                maxR1[r] = 0;
    }

    // ---- main loop: 16 rounds, drain-free double-barrier pipeline ----
#pragma unroll 1
    for (int r = 0; r < NRND; ++r) {
        // stage set r+1 into the opposite slot; its previous readers finished
        // at round r-1's barrier#2 (program order), so this cannot race.
        STAGE((r + 1) & (NRND - 1), (r + 1) & 1);    // wrap at tail: harmless
        asm volatile("s_waitcnt vmcnt(2)" ::: "memory");  // own round-r loads done
        __builtin_amdgcn_s_barrier();                // #1: set r valid block-wide
        __builtin_amdgcn_sched_barrier(0);           // fence code motion (rule #18)
        const int set = kh * NRND + r;               // ascending k within stream
        f32x4 eiv = *(const f32x4*)&eiL[set * 16 + g * 4];
        const char* ap = &ring[kh][r & 1][0] + (size_t)lane * 16;
        half8 ah0 = *(const half8*)(ap);
        half8 ah1 = *(const half8*)(ap + 1024);
        half8 al0 = *(const half8*)(ap + 2048);
        half8 al1 = *(const half8*)(ap + 3072);
        // two independent 6-chains (one per position tile), ei as C-init
        f32x4 a0 = __builtin_amdgcn_mfma_f32_16x16x32_f16(ah0, bh[0][0], eiv, 0, 0, 0);
        f32x4 a1 = __builtin_amdgcn_mfma_f32_16x16x32_f16(ah0, bh[1][0], eiv, 0, 0, 0);
        a0 = __builtin_amdgcn_mfma_f32_16x16x32_f16(ah1, bh[0][1], a0, 0, 0, 0);
        a1 = __builtin_amdgcn_mfma_f32_16x16x32_f16(ah1, bh[1][1], a1, 0, 0, 0);
        a0 = __builtin_amdgcn_mfma_f32_16x16x32_f16(ah0, bl[0][0], a0, 0, 0, 0);
        a1 = __builtin_amdgcn_mfma_f32_16x16x32_f16(ah0, bl[1][0], a1, 0, 0, 0);
        a0 = __builtin_amdgcn_mfma_f32_16x16x32_f16(ah1, bl[0][1], a0, 0, 0, 0);
        a1 = __builtin_amdgcn_mfma_f32_16x16x32_f16(ah1, bl[1][1], a1, 0, 0, 0);
        a0 = __builtin_amdgcn_mfma_f32_16x16x32_f16(al0, bh[0][0], a0, 0, 0, 0);
        a1 = __builtin_amdgcn_mfma_f32_16x16x32_f16(al0, bh[1][0], a1, 0, 0, 0);
        a0 = __builtin_amdgcn_mfma_f32_16x16x32_f16(al1, bh[0][1], a0, 0, 0, 0);
        a1 = __builtin_amdgcn_mfma_f32_16x16x32_f16(al1, bh[1][1], a1, 0, 0, 0);
        // vectorized per-r-slot argmax; sets ascend -> strict > keeps smallest k
#pragma unroll
        for (int rr = 0; rr < 4; ++rr) {
            if (a0[rr] > maxS0[rr]) { maxS0[rr] = a0[rr]; maxR0[rr] = set; }
            if (a1[rr] > maxS1[rr]) { maxS1[rr] = a1[rr]; maxR1[rr] = set; }
        }
        __builtin_amdgcn_s_barrier();                // #2: slot r&1 reads issued
    }
#undef STAGE

    // ---- per-lane lex fold (score desc, k asc), cross-g butterfly, publish ----
#pragma unroll
    for (int nt = 0; nt < 2; ++nt) {
        float bs = nt ? maxS1[0] : maxS0[0];
        int   bk = (nt ? maxR1[0] : maxR0[0]) * 16 + g * 4;
#pragma unroll
        for (int rr = 1; rr < 4; ++rr) {
            float sc = nt ? maxS1[rr] : maxS0[rr];
            int   kk = (nt ? maxR1[rr] : maxR0[rr]) * 16 + g * 4 + rr;
            if (sc > bs || (sc == bs && kk < bk)) { bs = sc; bk = kk; }
        }
#pragma unroll
        for (int m = 16; m <= 32; m <<= 1) {         // combine the 4 row-groups
            float os = __shfl_xor(bs, m);
            int   ok = __shfl_xor(bk, m);
            if (os > bs || (os == bs && ok < bk)) { bs = os; bk = ok; }
        }
        if (g == 0) {
            candS[kh][pg * 32 + nt * 16 + col] = bs;
            candK[kh][pg * 32 + nt * 16 + col] = bk;
        }
    }
    __syncthreads();

    // ---- combine the 4 codebook quarters (kh ascending -> lex), write indices ----
    if (tid < BPOS) {
        float bs = candS[0][tid];
        int   bk = candK[0][tid];
#pragma unroll
        for (int w = 1; w < 4; ++w) {
            float sc = candS[w][tid];
            int   kk = candK[w][tid];
            if (sc > bs || (sc == bs && kk < bk)) { bs = sc; bk = kk; }
        }
        kwin[tid] = bk;
        out[OUT_IDX + p0 + tid] = (float)bk;
    }
    __syncthreads();

    // ---- epilogue: coalesced q stores, exact f32 x re-read (L2-hot), loss ----
    float lsum = 0.f;
    {
        int p = tid & 63, cq = tid >> 6;
        int kk = kwin[p];
        const float* eb = emb + (size_t)kk * CDIM;
        float* q = out + OUT_Q + (size_t)b * (CDIM * SPATIAL) + s0;
#pragma unroll
        for (int j = 0; j < 8; ++j) {
            int c = cq * 8 + j;
            float x = xin[(size_t)c * SPATIAL + p];
            float e = eb[c];
            float d = e - x;                         // stop_grad(q - x)
            lsum = fmaf(d, d, lsum);
            q[(size_t)c * SPATIAL + p] = x + d;      // straight-through
        }
    }
#pragma unroll
    for (int off = 32; off > 0; off >>= 1) lsum += __shfl_down(lsum, off);
    if (lane == 0) lred[wv] = lsum;
    __syncthreads();
    if (tid == 0) {
        float t = 0.f;
#pragma unroll
        for (int w = 0; w < 8; ++w) t += lred[w];
        atomicAdd(out + OUT_LOSS, t * (0.25f / (float)NEL));
    }
}

extern "C" void kernel_launch(void* const* d_in, const int* in_sizes, int n_in,
                              void* d_out, int out_size, void* d_ws, size_t ws_size,
                              hipStream_t stream) {
    const float* in  = (const float*)d_in[0];   // [2,64,32,32,32] f32
    const float* emb = (const float*)d_in[1];   // [1024,64] f32
    float* out = (float*)d_out;
    char*  ws  = (char*)d_ws;                   // 266,240 B used

    prep_emb<<<64, 256, 0, stream>>>(emb, ws, out);
    vq_kernel<<<NPOS / BPOS, 512, 0, stream>>>(in, emb, ws, out);
}

// Round 16
// 44.787 us; speedup vs baseline: 2.3400x; 2.3400x over previous
//
#include <hip/hip_runtime.h>
#include <stdint.h>

#define KCODES  1024
#define CDIM    64
#define SPATIAL 32768
#define NPOS    65536
#define NEL     4194304

// d_out layout (floats), outputs concatenated in reference return order
#define OUT_Q    0
#define OUT_LOSS 4194304
#define OUT_IDX  4194305
#define OUT_SUM  4259841
#define OUT_EMB  4260097

// ws: 32 sets x 8KB {Ah0,Al0,Ah1,Al1,Ah2,Al2,Ah3,Al3} (1KB chunks, lane-linear),
// then eiExp[32][2][16] f32 at EIEXP: per-lane C-init vectors (-0.5*||e||^2)
#define NSET  32
#define SETB  8192
#define EIEXP 262144
#define BPOS  128
#define NPASS 4

typedef _Float16 half8  __attribute__((ext_vector_type(8)));
typedef float    f32x4  __attribute__((ext_vector_type(4)));
typedef float    f32x16 __attribute__((ext_vector_type(16)));

// ---- prep: fragment-swizzle codebook (32x32x16 A-frags), eiExp, zero, passthrough ----
__global__ void prep_emb(const float* __restrict__ emb, char* __restrict__ ws,
                         float* __restrict__ out) {
    int gt = blockIdx.x * 256 + threadIdx.x;        // 64 blocks -> 0..16383
    if (gt == 0) out[OUT_LOSS] = 0.f;
    if (gt < 256) out[OUT_SUM + gt] = 0.f;
    {   // embedding passthrough (OUT_EMB odd offset -> scalar stores)
        float4 v = *(const float4*)(emb + (size_t)gt * 4);
        float* o = out + OUT_EMB + (size_t)gt * 4;
        o[0] = v.x; o[1] = v.y; o[2] = v.z; o[3] = v.w;
    }
    if (gt < 8192) {                                 // one (code, 8-ch octet) each
        int k = gt >> 3, oct = gt & 7;
        int set = k >> 5, row = k & 31;
        int ks = oct >> 1, hc = oct & 1;             // c = ks*16 + hc*8 + i
        const float* e = emb + (size_t)k * CDIM + oct * 8;
        char* rec = ws + (size_t)set * SETB;
        // A-frag: lane l = hc*32+row holds 8 fp16 at chunk(ks,hi/lo) + l*16
        _Float16* hi = (_Float16*)(rec + (ks * 2 + 0) * 1024 + (hc * 32 + row) * 16);
        _Float16* lo = (_Float16*)(rec + (ks * 2 + 1) * 1024 + (hc * 32 + row) * 16);
        float s2 = 0.f;
        half8 hv, lv;
#pragma unroll
        for (int i = 0; i < 8; ++i) {
            float v = e[i];
            s2 = fmaf(v, v, s2);
            _Float16 h = (_Float16)v;
            hv[i] = h;
            lv[i] = (_Float16)(v - (float)h);
        }
        *(half8*)hi = hv;
        *(half8*)lo = lv;
        s2 += __shfl_xor(s2, 1);                     // reduce over the octet group
        s2 += __shfl_xor(s2, 2);
        s2 += __shfl_xor(s2, 4);
        if (oct == 0) {
            // C/D row = (q&3) + 8*(q>>2) + 4h  ->  h = bit2(row), q = (row&3)|((row>>3)<<2)
            int hh = (row >> 2) & 1;
            int q  = (row & 3) | ((row >> 3) << 2);
            ((float*)(ws + EIEXP))[(set * 2 + hh) * 16 + q] = -0.5f * s2;
        }
    }
}

// ---- main VQ kernel ----
// Grid 512 x 512 thr (8 waves), __launch_bounds__(512,2): 2 blocks/CU by LDS
// (74.7KB), ~110 unified regs -> 4 waves/SIMD. Block owns 128 positions.
// CODES-RESIDENT: per pass, wave wv holds A-frags of codes [set*32, set*32+32)
// in 32 VGPRs (set = pass*8+wv); positions stream as B-frags from LDS (built
// once in prologue, read-only). Main loop: ZERO global loads, ZERO barriers,
// ZERO staging -- fully independent waves (the only structure combining
// wave-independence + latency-free inner loop + 4 waves/SIMD).
// R8 verbatim except launch bounds: (512,4) capped VGPR at 64 and spilled
// (FETCH 228MB); (512,2) lets the ~110-reg working set allocate (R12-proven).
// ei folded via MFMA C-operand (eiExp). Score = x.e - 0.5||e||^2, argmax==argmin.
__global__ __launch_bounds__(512, 2) void vq_kernel(
        const float* __restrict__ in, const float* __restrict__ emb,
        const char* __restrict__ wsA, float* __restrict__ out) {
    __shared__ float xl[CDIM * 129];                 // 33 KB x transpose tile
    __shared__ __align__(16) char bfr[4 * 4 * 2 * 1024];  // 32 KB B-frags [t][ks][hl][lane*16]
    __shared__ float candS[8][BPOS];                 // per-wave per-pos best score
    __shared__ int   candK[8][BPOS];
    __shared__ int   kwin[BPOS];
    __shared__ float lred[8];

    const int tid  = threadIdx.x;
    const int lane = tid & 63, wv = tid >> 6;        // 8 waves
    const int col  = lane & 31, h = lane >> 5;
    const int p0   = blockIdx.x * BPOS;
    const int b    = p0 >> 15;                       // 128-tile never straddles batch
    const int s0   = p0 & 32767;
    const float* xin = in + (size_t)b * (CDIM * SPATIAL) + s0;

    // ---- prologue: x -> xl, init cand ----
    {
        int p = tid & 127, cq = tid >> 7;            // 4 ch-groups of 16
#pragma unroll
        for (int j = 0; j < 16; ++j) {
            int c = cq * 16 + j;
            xl[c * 129 + p] = xin[(size_t)c * SPATIAL + p];
        }
    }
#pragma unroll
    for (int i = tid; i < 8 * BPOS; i += 512) {
        candS[i >> 7][i & 127] = -3.402823466e38f;
        candK[i >> 7][i & 127] = 0;
    }
    __syncthreads();

    // ---- build B-frags (hi/lo fp16) from xl; layout matches MFMA B operand:
    // lane l: col = l&31 (position), k-local = (l>>5)*8 + i ----
#pragma unroll
    for (int s = tid; s < 1024; s += 512) {
        int t = s >> 8, ks = (s >> 6) & 3, l = s & 63;
        int pos = t * 32 + (l & 31);
        int c0  = ks * 16 + (l >> 5) * 8;
        half8 hv, lv;
#pragma unroll
        for (int i = 0; i < 8; ++i) {
            float v = xl[(c0 + i) * 129 + pos];
            _Float16 hh = (_Float16)v;
            hv[i] = hh;
            lv[i] = (_Float16)(v - (float)hh);
        }
        *(half8*)(bfr + (size_t)((t * 4 + ks) * 2 + 0) * 1024 + l * 16) = hv;
        *(half8*)(bfr + (size_t)((t * 4 + ks) * 2 + 1) * 1024 + l * 16) = lv;
    }
    __syncthreads();

    // ---- main: 4 passes x 4 tiles; A resident in regs, B from LDS, no barriers ----
#pragma unroll 1
    for (int pass = 0; pass < NPASS; ++pass) {
        const int set = pass * 8 + wv;
        const char* rec = wsA + (size_t)set * SETB;
        const char* ap  = rec + (size_t)lane * 16;
        half8 ah0 = *(const half8*)(ap);             // A-frags: 32 codes, once per pass
        half8 al0 = *(const half8*)(ap + 1024);
        half8 ah1 = *(const half8*)(ap + 2048);
        half8 al1 = *(const half8*)(ap + 3072);
        half8 ah2 = *(const half8*)(ap + 4096);
        half8 al2 = *(const half8*)(ap + 5120);
        half8 ah3 = *(const half8*)(ap + 6144);
        half8 al3 = *(const half8*)(ap + 7168);
        f32x16 eiv = *(const f32x16*)((const float*)(wsA + EIEXP) + (set * 2 + h) * 16);
        const int kbase = set * 32 + 4 * h;

#pragma unroll
        for (int t = 0; t < 4; ++t) {
            const char* bp = bfr + (size_t)t * 8192 + (size_t)lane * 16;
            half8 bh0 = *(const half8*)(bp);
            half8 bl0 = *(const half8*)(bp + 1024);
            half8 bh1 = *(const half8*)(bp + 2048);
            half8 bl1 = *(const half8*)(bp + 3072);
            half8 bh2 = *(const half8*)(bp + 4096);
            half8 bl2 = *(const half8*)(bp + 5120);
            half8 bh3 = *(const half8*)(bp + 6144);
            half8 bl3 = *(const half8*)(bp + 7168);
            f32x16 a;
            a = __builtin_amdgcn_mfma_f32_32x32x16_f16(ah0, bh0, eiv, 0, 0, 0);
            a = __builtin_amdgcn_mfma_f32_32x32x16_f16(ah0, bl0, a, 0, 0, 0);
            a = __builtin_amdgcn_mfma_f32_32x32x16_f16(al0, bh0, a, 0, 0, 0);
            a = __builtin_amdgcn_mfma_f32_32x32x16_f16(ah1, bh1, a, 0, 0, 0);
            a = __builtin_amdgcn_mfma_f32_32x32x16_f16(ah1, bl1, a, 0, 0, 0);
            a = __builtin_amdgcn_mfma_f32_32x32x16_f16(al1, bh1, a, 0, 0, 0);
            a = __builtin_amdgcn_mfma_f32_32x32x16_f16(ah2, bh2, a, 0, 0, 0);
            a = __builtin_amdgcn_mfma_f32_32x32x16_f16(ah2, bl2, a, 0, 0, 0);
            a = __builtin_amdgcn_mfma_f32_32x32x16_f16(al2, bh2, a, 0, 0, 0);
            a = __builtin_amdgcn_mfma_f32_32x32x16_f16(ah3, bh3, a, 0, 0, 0);
            a = __builtin_amdgcn_mfma_f32_32x32x16_f16(ah3, bl3, a, 0, 0, 0);
            a = __builtin_amdgcn_mfma_f32_32x32x16_f16(al3, bh3, a, 0, 0, 0);

            // fold: k(q) = kbase + (q&3) + 8*(q>>2), strictly ascending in q
            // -> linear strict-> scan keeps smallest k on ties
            float bs = a[0];
            int   bk = kbase;
#pragma unroll
            for (int q = 1; q < 16; ++q) {
                float sc = a[q];
                int   kk = kbase + (q & 3) + 8 * (q >> 2);
                if (sc > bs) { bs = sc; bk = kk; }
            }
            // h-combine (k interleaves across h -> lex)
            {
                float os = __shfl_xor(bs, 32);
                int   ok = __shfl_xor(bk, 32);
                if (os > bs || (os == bs && ok < bk)) { bs = os; bk = ok; }
            }
            // per-wave running best in LDS (owner-wave RMW, no race);
            // passes ascend in k -> strict > keeps smaller k on ties
            if (h == 0) {
                int pc = t * 32 + col;
                float cs = candS[wv][pc];
                if (bs > cs) { candS[wv][pc] = bs; candK[wv][pc] = bk; }
            }
        }
    }
    __syncthreads();

    // ---- final 8-way lex combine, write indices ----
    if (tid < BPOS) {
        int p = tid;
        float bs = candS[0][p];
        int   bk = candK[0][p];
#pragma unroll
        for (int w = 1; w < 8; ++w) {
            float sc = candS[w][p];
            int   kk = candK[w][p];
            if (sc > bs || (sc == bs && kk < bk)) { bs = sc; bk = kk; }
        }
        kwin[p] = bk;
        out[OUT_IDX + p0 + p] = (float)bk;
    }
    __syncthreads();

    // ---- epilogue: coalesced q stores, exact f32 x re-read (L3-hot), loss ----
    float lsum = 0.f;
    {
        int p = tid & 127, cq = tid >> 7;
        int kk = kwin[p];
        const float* eb = emb + (size_t)kk * CDIM;
        float* q = out + OUT_Q + (size_t)b * (CDIM * SPATIAL) + s0;
#pragma unroll
        for (int j = 0; j < 16; ++j) {
            int c = cq * 16 + j;
            float x = xin[(size_t)c * SPATIAL + p];
            float e = eb[c];
            float d = e - x;                         // stop_grad(q - x)
            lsum = fmaf(d, d, lsum);
            q[(size_t)c * SPATIAL + p] = x + d;      // straight-through
        }
    }
#pragma unroll
    for (int off = 32; off > 0; off >>= 1) lsum += __shfl_down(lsum, off);
    if (lane == 0) lred[wv] = lsum;
    __syncthreads();
    if (tid == 0) {
        float t = 0.f;
#pragma unroll
        for (int w = 0; w < 8; ++w) t += lred[w];
        atomicAdd(out + OUT_LOSS, t * (0.25f / (float)NEL));
    }
}

extern "C" void kernel_launch(void* const* d_in, const int* in_sizes, int n_in,
                              void* d_out, int out_size, void* d_ws, size_t ws_size,
                              hipStream_t stream) {
    const float* in  = (const float*)d_in[0];   // [2,64,32,32,32] f32
    const float* emb = (const float*)d_in[1];   // [1024,64] f32
    float* out = (float*)d_out;
    char*  ws  = (char*)d_ws;                   // 266,240 B used

    prep_emb<<<64, 256, 0, stream>>>(emb, ws, out);
    vq_kernel<<<NPOS / BPOS, 512, 0, stream>>>(in, emb, ws, out);
}